// Round 3
// baseline (16288.051 us; speedup 1.0000x reference)
//
#include <hip/hip_runtime.h>

// ---------------------------------------------------------------------------
// GRU forecaster: B=32, T=2048, I=256, H=512, L=2, O=64   (all-f16 datapath)
// Per chunk: GEMM(xi, f16 MFMA, fused cast) -> cooperative scan.
// Scan: 16 clusters x 16 WGs (1 WG/CU, 96KB f16 weight slice in LDS),
//   per-wave full reduction (shfl_xor over kseg lanes), 4 finalize lanes/wave,
//   single barrier/step (parity-double-buffered Lh), h exchange via
//   epoch-stamped 8B agent-scope atomics, xi prefetched one step ahead.
// ---------------------------------------------------------------------------

typedef unsigned int  u32;
typedef unsigned short u16;
typedef unsigned long long u64;
typedef float v4f __attribute__((ext_vector_type(4)));
typedef _Float16 v2h __attribute__((ext_vector_type(2)));
typedef _Float16 v8h __attribute__((ext_vector_type(8)));

#if defined(__has_builtin)
#  if __has_builtin(__builtin_amdgcn_fdot2)
#    define FDOT2(a, b, c) __builtin_amdgcn_fdot2((a), (b), (c), false)
#  endif
#endif
#ifndef FDOT2
#  define FDOT2(a, b, c) ((c) + (float)(a)[0] * (float)(b)[0] + (float)(a)[1] * (float)(b)[1])
#endif

__device__ __forceinline__ u16 f2h(float f) {
    _Float16 h = (_Float16)f;
    return *(u16*)&h;
}
__device__ __forceinline__ float h2f(u16 b) {
    _Float16 h = *(_Float16*)&b;
    return (float)h;
}

// --------------------------- prep kernels ----------------------------------

// src fp32 [R][C] -> dst f16 [C][R]  (32x32 tiles)
__global__ __launch_bounds__(256) void transpose_cast(const float* __restrict__ src,
                                                      u16* __restrict__ dst,
                                                      int R, int C) {
    __shared__ u16 tile[32][33];
    int c0 = blockIdx.x * 32, r0 = blockIdx.y * 32;
    int t = threadIdx.x;
    {
        int rl = t >> 3, cl4 = (t & 7) * 4;
        float4 v = *(const float4*)&src[(size_t)(r0 + rl) * C + c0 + cl4];
        tile[rl][cl4 + 0] = f2h(v.x);
        tile[rl][cl4 + 1] = f2h(v.y);
        tile[rl][cl4 + 2] = f2h(v.z);
        tile[rl][cl4 + 3] = f2h(v.w);
    }
    __syncthreads();
    {
        int cl = t >> 3, rl4 = (t & 7) * 4;
        uint2 o;
        o.x = (u32)tile[rl4 + 0][cl] | ((u32)tile[rl4 + 1][cl] << 16);
        o.y = (u32)tile[rl4 + 2][cl] | ((u32)tile[rl4 + 3][cl] << 16);
        *(uint2*)&dst[(size_t)(c0 + cl) * R + r0 + rl4] = o;
    }
}

// Wh fp32 [512][1536] -> f16 packed for the scan's lane-contiguous ds_read:
// slot id = m*6144 + ((w*12 + g*4 + qk)*64 + kseg*4 + jl), 8 f16/slot:
//   j = m*32 + w*4 + jl, col = g*512 + j, k = kseg*32 + qk*8 + i.
__global__ __launch_bounds__(256) void pack_wh(const float* __restrict__ Wh,
                                               uint4* __restrict__ dst) {
    int id = blockIdx.x * 256 + threadIdx.x;   // < 98304
    int m = id / 6144, s = id % 6144;
    int top = s >> 6, low = s & 63;
    int w = top / 12, gq = top % 12;
    int g = gq >> 2, qk = gq & 3;
    int kseg = low >> 2, jl = low & 3;
    int col = g * 512 + m * 32 + w * 4 + jl;
    int kb = kseg * 32 + qk * 8;
    u32 d[4];
#pragma unroll
    for (int p = 0; p < 4; ++p) {
        u16 a = f2h(Wh[(size_t)(kb + 2 * p) * 1536 + col]);
        u16 b = f2h(Wh[(size_t)(kb + 2 * p + 1) * 1536 + col]);
        d[p] = (u32)a | ((u32)b << 16);
    }
    uint4 o; o.x = d[0]; o.y = d[1]; o.z = d[2]; o.w = d[3];
    dst[id] = o;
}

// ---------------- GEMM: xi_chunk = A_rows @ Bt^T + bias -> f16 --------------
// A: rows (b*2048 + t0 + tl), fp32 (layer0) or f16 (layer1), K cols.
// Bt: [1536][K] f16. C: [32*Tc][1536] f16, row m = b*Tc + tl (chunk-local).
template <int K, bool AF32>
__global__ __launch_bounds__(256) void gemm_xi(const void* __restrict__ Ap,
                                               const u16* __restrict__ Bt,
                                               const float* __restrict__ bias,
                                               u16* __restrict__ C,
                                               int t0, int lgTc) {
    __shared__ u16 As[64 * 40];   // 64 rows x 32 k, stride 40 (pad)
    __shared__ u16 Bs[64 * 40];
    const int tid = threadIdx.x;
    const int n0 = blockIdx.x * 64;
    const int m0 = blockIdx.y * 64;
    const int row = tid >> 2, koff = (tid & 3) * 8;
    const int lane = tid & 63, w = tid >> 6;
    const int m = m0 + row;
    const int b = m >> lgTc;
    const int tl = m & ((1 << lgTc) - 1);
    const size_t srow = ((size_t)b << 11) + (size_t)(t0 + tl);
    v4f acc[4];
#pragma unroll
    for (int i = 0; i < 4; ++i) acc[i] = (v4f){0.f, 0.f, 0.f, 0.f};

    for (int k0 = 0; k0 < K; k0 += 32) {
        if (AF32) {
            const float* A = (const float*)Ap;
            float4 v0 = *(const float4*)&A[srow * K + k0 + koff];
            float4 v1 = *(const float4*)&A[srow * K + k0 + koff + 4];
            uint4 o;
            o.x = (u32)f2h(v0.x) | ((u32)f2h(v0.y) << 16);
            o.y = (u32)f2h(v0.z) | ((u32)f2h(v0.w) << 16);
            o.z = (u32)f2h(v1.x) | ((u32)f2h(v1.y) << 16);
            o.w = (u32)f2h(v1.z) | ((u32)f2h(v1.w) << 16);
            *(uint4*)&As[row * 40 + koff] = o;
        } else {
            const u16* A = (const u16*)Ap;
            *(uint4*)&As[row * 40 + koff] =
                *(const uint4*)&A[srow * K + k0 + koff];
        }
        *(uint4*)&Bs[row * 40 + koff] =
            *(const uint4*)&Bt[(size_t)(n0 + row) * K + k0 + koff];
        __syncthreads();
        v8h a = *(const v8h*)&As[(w * 16 + (lane & 15)) * 40 + (lane >> 4) * 8];
#pragma unroll
        for (int nt = 0; nt < 4; ++nt) {
            v8h bm = *(const v8h*)&Bs[(nt * 16 + (lane & 15)) * 40 + (lane >> 4) * 8];
            acc[nt] = __builtin_amdgcn_mfma_f32_16x16x32_f16(a, bm, acc[nt], 0, 0, 0);
        }
        __syncthreads();
    }
#pragma unroll
    for (int nt = 0; nt < 4; ++nt) {
        int col = n0 + nt * 16 + (lane & 15);
        float bv = bias[col];
#pragma unroll
        for (int rI = 0; rI < 4; ++rI) {
            int rowm = m0 + w * 16 + (lane >> 4) * 4 + rI;
            C[(size_t)rowm * 1536 + col] = f2h(acc[nt][rI] + bv);
        }
    }
}

// --------------------------- GRU scan (cooperative) -------------------------
// grid = 256 x 512. cluster = blockIdx & 15, member = blockIdx >> 4.
// Cluster c owns batches {2c, 2c+1}; member m owns j in [32m, 32m+32).
// Wave w owns j = 32m + 4w + jl (jl = lane>>4); kseg = lane & 15 covers 32 k.
__global__ __launch_bounds__(512) void gru_scan(const u16* __restrict__ xi,
                                                const uint4* __restrict__ Whp,
                                                const float* __restrict__ bhn,
                                                u64* __restrict__ Hbuf,
                                                u32* __restrict__ hseq,
                                                float* __restrict__ h1last,
                                                float* __restrict__ hstate,
                                                int t0, int Tc, int layer0) {
    __shared__ uint4 LW[6144];                       // 96KB f16 weight slice
    __shared__ __align__(16) u16 Lhh[2][2 * 512];    // parity x (batch,k) f16

    const int tid = threadIdx.x;
    const int wg = blockIdx.x;
    const int cluster = wg & 15;
    const int member = wg >> 4;

    // stage weight slice (contiguous per member)
    {
        const uint4* src = Whp + (size_t)member * 6144;
#pragma unroll
        for (int i = 0; i < 12; ++i) LW[tid + 512 * i] = src[tid + 512 * i];
    }

    const int w = tid >> 6, lane = tid & 63;
    const int jl = lane >> 4, kseg = lane & 15;
    const int j = member * 32 + w * 4 + jl;
    const bool fin = (kseg == 0);
    const int bg0 = cluster * 2, bg1 = bg0 + 1;

    // init parity buffer (t0&1) with h_{t0-1}
    {
        u32 v = 0;
        if (t0 > 0) v = (u32)Hbuf[(size_t)(cluster * 2 + ((t0 - 1) & 1)) * 512 + tid];
        ((u32*)Lhh[t0 & 1])[tid] = v;
    }
    float hprev0 = 0.f, hprev1 = 0.f, bhnv = 0.f;
    u16 rx0 = 0, rz0 = 0, rn0 = 0, rx1 = 0, rz1 = 0, rn1 = 0;
    if (fin) {
        bhnv = bhn[j];
        if (t0 > 0) {
            hprev0 = hstate[bg0 * 512 + j];
            hprev1 = hstate[bg1 * 512 + j];
        }
        const u16* p0 = xi + (size_t)bg0 * Tc * 1536 + j;
        const u16* p1 = xi + (size_t)bg1 * Tc * 1536 + j;
        rx0 = p0[0]; rz0 = p0[512]; rn0 = p0[1024];
        rx1 = p1[0]; rz1 = p1[512]; rn1 = p1[1024];
    }
    __syncthreads();

    for (int t = t0; t < t0 + Tc; ++t) {
        const u16* lhp = Lhh[t & 1];
        // ---- dot partials: lane (jl,kseg) covers k in [32*kseg, +32), 3g x 2b
        float acc00 = 0.f, acc01 = 0.f, acc10 = 0.f, acc11 = 0.f, acc20 = 0.f, acc21 = 0.f;
#pragma unroll
        for (int qk = 0; qk < 4; ++qk) {
            v8h h0 = *(const v8h*)&lhp[kseg * 32 + qk * 8];
            v8h h1 = *(const v8h*)&lhp[512 + kseg * 32 + qk * 8];
            const v2h* h0p = (const v2h*)&h0;
            const v2h* h1p = (const v2h*)&h1;
            const u16* wbase = (const u16*)LW + ((w * 12 + qk) * 64 + kseg * 4 + jl) * 8;
#pragma unroll
            for (int g = 0; g < 3; ++g) {
                v8h wv = *(const v8h*)&wbase[g * 4 * 64 * 8];
                const v2h* wp = (const v2h*)&wv;
#pragma unroll
                for (int p2 = 0; p2 < 4; ++p2) {
                    float* a0 = (g == 0) ? &acc00 : (g == 1) ? &acc10 : &acc20;
                    float* a1 = (g == 0) ? &acc01 : (g == 1) ? &acc11 : &acc21;
                    *a0 = FDOT2(wp[p2], h0p[p2], *a0);
                    *a1 = FDOT2(wp[p2], h1p[p2], *a1);
                }
            }
        }
        // ---- reduce over kseg (low 4 lane bits)
#pragma unroll
        for (int d = 1; d <= 8; d <<= 1) {
            acc00 += __shfl_xor(acc00, d); acc01 += __shfl_xor(acc01, d);
            acc10 += __shfl_xor(acc10, d); acc11 += __shfl_xor(acc11, d);
            acc20 += __shfl_xor(acc20, d); acc21 += __shfl_xor(acc21, d);
        }
        u64* slot = Hbuf + (size_t)(cluster * 2 + (t & 1)) * 512;
        u32 myp0 = 0, myp1 = 0;
        if (fin) {
            // batch 0
            float r = 1.f / (1.f + __expf(-(h2f(rx0) + acc00)));
            float z = 1.f / (1.f + __expf(-(h2f(rz0) + acc10)));
            float nx = h2f(rn0) + r * (acc20 + bhnv);
            float n = 1.f - 2.f / (__expf(2.f * nx) + 1.f);
            float hn0 = (1.f - z) * n + z * hprev0;
            hprev0 = hn0;
            // batch 1
            r = 1.f / (1.f + __expf(-(h2f(rx1) + acc01)));
            z = 1.f / (1.f + __expf(-(h2f(rz1) + acc11)));
            nx = h2f(rn1) + r * (acc21 + bhnv);
            n = 1.f - 2.f / (__expf(2.f * nx) + 1.f);
            float hn1 = (1.f - z) * n + z * hprev1;
            hprev1 = hn1;
            myp0 = (u32)f2h(hn0);
            myp1 = (u32)f2h(hn1);
        }
        // pair exchange: lane jl even takes jl+1's value (lane+16)
        u32 q0 = (u32)__shfl((int)myp0, lane + 16);
        u32 q1 = (u32)__shfl((int)myp1, lane + 16);
        if (fin && (jl & 1) == 0) {
            u32 pair0 = myp0 | (q0 << 16);
            u32 pair1 = myp1 | (q1 << 16);
            int pidx = j >> 1;
            u64 e = (u64)(u32)(t + 1) << 32;
            __hip_atomic_store(&slot[pidx], (u64)pair0 | e,
                               __ATOMIC_RELAXED, __HIP_MEMORY_SCOPE_AGENT);
            __hip_atomic_store(&slot[256 + pidx], (u64)pair1 | e,
                               __ATOMIC_RELAXED, __HIP_MEMORY_SCOPE_AGENT);
            if (layer0) {
                hseq[((size_t)bg0 * 2048 + t) * 256 + pidx] = pair0;
                hseq[((size_t)bg1 * 2048 + t) * 256 + pidx] = pair1;
            }
        }
        if (fin) {
            if (!layer0 && t == 2047) {
                h1last[bg0 * 512 + j] = hprev0;
                h1last[bg1 * 512 + j] = hprev1;
            }
            if (t + 1 < t0 + Tc) {   // prefetch xi for t+1 (hidden by poll+compute)
                int tl = t + 1 - t0;
                const u16* p0 = xi + ((size_t)bg0 * Tc + tl) * 1536 + j;
                const u16* p1 = xi + ((size_t)bg1 * Tc + tl) * 1536 + j;
                rx0 = p0[0]; rz0 = p0[512]; rn0 = p0[1024];
                rx1 = p1[0]; rz1 = p1[512]; rn1 = p1[1024];
            }
        }
        // ---- poll own qword (data IS the flag), fill next parity buffer
        {
            const u32 target = (u32)(t + 1);
            u64* myq = &slot[tid];
            u64 qv = 0;
            for (int it = 0; it < 4000000; ++it) {
                qv = __hip_atomic_load(myq, __ATOMIC_RELAXED, __HIP_MEMORY_SCOPE_AGENT);
                if ((u32)(qv >> 32) == target) break;
                __builtin_amdgcn_s_sleep(1);
            }
            ((u32*)Lhh[(t + 1) & 1])[tid] = (u32)qv;
        }
        __syncthreads();
    }
    if (fin) {
        hstate[bg0 * 512 + j] = hprev0;
        hstate[bg1 * 512 + j] = hprev1;
    }
}

// --------------------------- final FC --------------------------------------
__global__ __launch_bounds__(64) void final_fc(const float* __restrict__ h1,
                                               const float* __restrict__ Wfc,
                                               const float* __restrict__ bfc,
                                               float* __restrict__ out) {
    int b = blockIdx.x, o = threadIdx.x;
    float acc = bfc[o];
    for (int k = 0; k < 512; ++k) acc += h1[b * 512 + k] * Wfc[k * 64 + o];
    out[b * 64 + o] = acc;
}

// --------------------------- launch ----------------------------------------

extern "C" void kernel_launch(void* const* d_in, const int* in_sizes, int n_in,
                              void* d_out, int out_size, void* d_ws, size_t ws_size,
                              hipStream_t stream) {
    const float* x    = (const float*)d_in[0];
    const float* Wi0  = (const float*)d_in[1];
    const float* bi0  = (const float*)d_in[2];
    const float* Wh0  = (const float*)d_in[3];
    const float* bhn0 = (const float*)d_in[4];
    const float* Wi1  = (const float*)d_in[5];
    const float* bi1  = (const float*)d_in[6];
    const float* Wh1  = (const float*)d_in[7];
    const float* bhn1 = (const float*)d_in[8];
    const float* Wfc  = (const float*)d_in[9];
    const float* bfc  = (const float*)d_in[10];
    float* out = (float*)d_out;
    (void)in_sizes; (void)n_in; (void)out_size;

    char* ws = (char*)d_ws;
    size_t off = 0;
    auto take = [&](size_t bytes) -> char* {
        char* p = ws + off;
        off = (off + bytes + 255) & ~(size_t)255;
        return p;
    };
    u16*  Wi0t  = (u16*)take(1536 * 256 * 2);
    u16*  Wi1t  = (u16*)take(1536 * 512 * 2);
    uint4* Wh0p = (uint4*)take(98304 * 16);
    uint4* Wh1p = (uint4*)take(98304 * 16);
    u64*  Hb0   = (u64*)take(32 * 512 * 8);
    u64*  Hb1   = (u64*)take(32 * 512 * 8);
    float* hstate = (float*)take(32 * 512 * 4);
    float* h1last = (float*)take(32 * 512 * 4);
    u16*  h0seq = (u16*)take((size_t)32 * 2048 * 512 * 2);
    size_t fixed_end = off;

    int Tc = 2048;
    if (ws_size > 0) {
        while (Tc > 128 &&
               fixed_end + (size_t)32 * Tc * 1536 * 2 > ws_size) Tc >>= 1;
    }
    int lgTc = 31 - __builtin_clz((u32)Tc);
    u16* xibuf = (u16*)take((size_t)32 * Tc * 1536 * 2);
    int nChunk = 2048 / Tc;

    // prep
    transpose_cast<<<dim3(48, 8), 256, 0, stream>>>(Wi0, Wi0t, 256, 1536);
    transpose_cast<<<dim3(48, 16), 256, 0, stream>>>(Wi1, Wi1t, 512, 1536);
    pack_wh<<<384, 256, 0, stream>>>(Wh0, Wh0p);
    pack_wh<<<384, 256, 0, stream>>>(Wh1, Wh1p);

    // layer 0
    for (int c = 0; c < nChunk; ++c) {
        int t0 = c * Tc;
        gemm_xi<256, true><<<dim3(24, Tc / 2), 256, 0, stream>>>(
            (const void*)x, Wi0t, bi0, xibuf, t0, lgTc);
        const u16* xi_p = xibuf; const uint4* wh_p = Wh0p; const float* bh_p = bhn0;
        u64* hb_p = Hb0; u32* hs_p = (u32*)h0seq; float* h1_p = nullptr;
        float* st_p = hstate; int t0v = t0, Tcv = Tc, l0v = 1;
        void* args[] = {&xi_p, &wh_p, &bh_p, &hb_p, &hs_p, &h1_p, &st_p,
                        &t0v, &Tcv, &l0v};
        hipLaunchCooperativeKernel(gru_scan, dim3(256), dim3(512), args, 0, stream);
    }
    // layer 1
    for (int c = 0; c < nChunk; ++c) {
        int t0 = c * Tc;
        gemm_xi<512, false><<<dim3(24, Tc / 2), 256, 0, stream>>>(
            (const void*)h0seq, Wi1t, bi1, xibuf, t0, lgTc);
        const u16* xi_p = xibuf; const uint4* wh_p = Wh1p; const float* bh_p = bhn1;
        u64* hb_p = Hb1; u32* hs_p = nullptr; float* h1_p = h1last;
        float* st_p = hstate; int t0v = t0, Tcv = Tc, l0v = 0;
        void* args[] = {&xi_p, &wh_p, &bh_p, &hb_p, &hs_p, &h1_p, &st_p,
                        &t0v, &Tcv, &l0v};
        hipLaunchCooperativeKernel(gru_scan, dim3(256), dim3(512), args, 0, stream);
    }
    final_fc<<<32, 64, 0, stream>>>(h1last, Wfc, bfc, out);
}

// Round 4
// 8679.089 us; speedup vs baseline: 1.8767x; 1.8767x over previous
//
#include <hip/hip_runtime.h>

// ---------------------------------------------------------------------------
// GRU forecaster: B=32, T=2048, I=256, H=512, L=2, O=64   (f16 datapath)
// Scan: 32 clusters (1 batch each) x 8 WGs (1 WG/CU). Member owns 64 j's;
// weights live in VGPRs (uint4 Wreg[24], 384B/thread). h exchanged as u32
// {epoch<<16|f16} agent-scope atomics; LDS h buffer XOR-swizzled (conflict-
// free ds_read_b128). One barrier/step, xi prefetched one step ahead.
// ---------------------------------------------------------------------------

typedef unsigned int  u32;
typedef unsigned short u16;
typedef float v4f __attribute__((ext_vector_type(4)));
typedef _Float16 v2h __attribute__((ext_vector_type(2)));
typedef _Float16 v8h __attribute__((ext_vector_type(8)));

#if defined(__has_builtin)
#  if __has_builtin(__builtin_amdgcn_fdot2)
#    define FDOT2(a, b, c) __builtin_amdgcn_fdot2((a), (b), (c), false)
#  endif
#endif
#ifndef FDOT2
#  define FDOT2(a, b, c) ((c) + (float)(a)[0] * (float)(b)[0] + (float)(a)[1] * (float)(b)[1])
#endif

__device__ __forceinline__ u16 f2h(float f) {
    _Float16 h = (_Float16)f;
    return *(u16*)&h;
}
__device__ __forceinline__ float h2f(u16 b) {
    _Float16 h = *(_Float16*)&b;
    return (float)h;
}

// --------------------------- prep kernels ----------------------------------

// src fp32 [R][C] -> dst f16 [C][R]  (32x32 tiles)
__global__ __launch_bounds__(256) void transpose_cast(const float* __restrict__ src,
                                                      u16* __restrict__ dst,
                                                      int R, int C) {
    __shared__ u16 tile[32][33];
    int c0 = blockIdx.x * 32, r0 = blockIdx.y * 32;
    int t = threadIdx.x;
    {
        int rl = t >> 3, cl4 = (t & 7) * 4;
        float4 v = *(const float4*)&src[(size_t)(r0 + rl) * C + c0 + cl4];
        tile[rl][cl4 + 0] = f2h(v.x);
        tile[rl][cl4 + 1] = f2h(v.y);
        tile[rl][cl4 + 2] = f2h(v.z);
        tile[rl][cl4 + 3] = f2h(v.w);
    }
    __syncthreads();
    {
        int cl = t >> 3, rl4 = (t & 7) * 4;
        uint2 o;
        o.x = (u32)tile[rl4 + 0][cl] | ((u32)tile[rl4 + 1][cl] << 16);
        o.y = (u32)tile[rl4 + 2][cl] | ((u32)tile[rl4 + 3][cl] << 16);
        *(uint2*)&dst[(size_t)(c0 + cl) * R + r0 + rl4] = o;
    }
}

// Wh fp32 [512][1536] -> f16 regs layout: uint4 index ((m*8+w)*24 + c)*64 + lane,
// lane = kseg*8+jb, c = g*8+qk; holds Wh[k = kseg*64+qk*8+i][g*512 + m*64+w*8+jb].
__global__ __launch_bounds__(256) void pack_wh(const float* __restrict__ Wh,
                                               uint4* __restrict__ dst) {
    int id = blockIdx.x * 256 + threadIdx.x;   // < 98304
    int lane = id & 63;
    int c = (id >> 6) % 24;
    int mw = id / 1536;                        // m*8 + w
    int kseg = lane >> 3, jb = lane & 7;
    int g = c >> 3, qk = c & 7;
    int col = g * 512 + (mw >> 3) * 64 + (mw & 7) * 8 + jb;
    int kb = kseg * 64 + qk * 8;
    u32 d[4];
#pragma unroll
    for (int p = 0; p < 4; ++p) {
        u16 a = f2h(Wh[(size_t)(kb + 2 * p) * 1536 + col]);
        u16 b = f2h(Wh[(size_t)(kb + 2 * p + 1) * 1536 + col]);
        d[p] = (u32)a | ((u32)b << 16);
    }
    uint4 o; o.x = d[0]; o.y = d[1]; o.z = d[2]; o.w = d[3];
    dst[id] = o;
}

// ---------------- GEMM: xi_chunk = A_rows @ Bt^T + bias -> f16 --------------
template <int K, bool AF32>
__global__ __launch_bounds__(256) void gemm_xi(const void* __restrict__ Ap,
                                               const u16* __restrict__ Bt,
                                               const float* __restrict__ bias,
                                               u16* __restrict__ C,
                                               int t0, int lgTc) {
    __shared__ u16 As[64 * 40];
    __shared__ u16 Bs[64 * 40];
    const int tid = threadIdx.x;
    const int n0 = blockIdx.x * 64;
    const int m0 = blockIdx.y * 64;
    const int row = tid >> 2, koff = (tid & 3) * 8;
    const int lane = tid & 63, w = tid >> 6;
    const int m = m0 + row;
    const int b = m >> lgTc;
    const int tl = m & ((1 << lgTc) - 1);
    const size_t srow = ((size_t)b << 11) + (size_t)(t0 + tl);
    v4f acc[4];
#pragma unroll
    for (int i = 0; i < 4; ++i) acc[i] = (v4f){0.f, 0.f, 0.f, 0.f};

    for (int k0 = 0; k0 < K; k0 += 32) {
        if (AF32) {
            const float* A = (const float*)Ap;
            float4 v0 = *(const float4*)&A[srow * K + k0 + koff];
            float4 v1 = *(const float4*)&A[srow * K + k0 + koff + 4];
            uint4 o;
            o.x = (u32)f2h(v0.x) | ((u32)f2h(v0.y) << 16);
            o.y = (u32)f2h(v0.z) | ((u32)f2h(v0.w) << 16);
            o.z = (u32)f2h(v1.x) | ((u32)f2h(v1.y) << 16);
            o.w = (u32)f2h(v1.z) | ((u32)f2h(v1.w) << 16);
            *(uint4*)&As[row * 40 + koff] = o;
        } else {
            const u16* A = (const u16*)Ap;
            *(uint4*)&As[row * 40 + koff] =
                *(const uint4*)&A[srow * K + k0 + koff];
        }
        *(uint4*)&Bs[row * 40 + koff] =
            *(const uint4*)&Bt[(size_t)(n0 + row) * K + k0 + koff];
        __syncthreads();
        v8h a = *(const v8h*)&As[(w * 16 + (lane & 15)) * 40 + (lane >> 4) * 8];
#pragma unroll
        for (int nt = 0; nt < 4; ++nt) {
            v8h bm = *(const v8h*)&Bs[(nt * 16 + (lane & 15)) * 40 + (lane >> 4) * 8];
            acc[nt] = __builtin_amdgcn_mfma_f32_16x16x32_f16(a, bm, acc[nt], 0, 0, 0);
        }
        __syncthreads();
    }
#pragma unroll
    for (int nt = 0; nt < 4; ++nt) {
        int col = n0 + nt * 16 + (lane & 15);
        float bv = bias[col];
#pragma unroll
        for (int rI = 0; rI < 4; ++rI) {
            int rowm = m0 + w * 16 + (lane >> 4) * 4 + rI;
            C[(size_t)rowm * 1536 + col] = f2h(acc[nt][rI] + bv);
        }
    }
}

// --------------------------- GRU scan (cooperative) -------------------------
// grid = 256 x 512. cluster = wg & 31 (= batch), member = wg >> 5.
// Member owns j in [member*64, +64). Thread (w, lane): kseg = lane>>3 covers
// k in [kseg*64,+64), jb = lane&7, j = member*64 + w*8 + jb.
// Weights in VGPRs. h in LDS, XOR-swizzled: h[k] at u16 index
// (kseg*8 + (qk^kseg))*8 + i  (k = kseg*64+qk*8+i).
__global__ __launch_bounds__(512, 2) void gru_scan(const u16* __restrict__ xi,
                                                   const uint4* __restrict__ Whp,
                                                   const float* __restrict__ bhn,
                                                   u32* __restrict__ Hb,
                                                   u16* __restrict__ hseq,
                                                   float* __restrict__ h1last,
                                                   float* __restrict__ hstate,
                                                   int t0, int Tc, int layer0) {
    __shared__ __align__(16) u16 Lhh[2][512];

    const int tid = threadIdx.x;
    const int wg = blockIdx.x;
    const int cluster = wg & 31;          // batch
    const int member = wg >> 5;
    const int w = tid >> 6, lane = tid & 63;
    const int kseg = lane >> 3, jb = lane & 7;
    const int j = member * 64 + w * 8 + jb;
    const bool fin = (kseg == 0);
    const int bg = cluster;

    // weights -> VGPRs (coalesced: per c, 64 lanes read 1KB contiguous)
    uint4 Wreg[24];
    {
        const uint4* src = Whp + ((size_t)(member * 8 + w) * 24) * 64 + lane;
#pragma unroll
        for (int c = 0; c < 24; ++c) Wreg[c] = src[c * 64];
    }

    // swizzled write index for k = tid (loop-invariant)
    const int pks = tid >> 6, pqk = (tid >> 3) & 7, pi = tid & 7;
    const int physw = (pks * 8 + (pqk ^ pks)) * 8 + pi;

    // init parity (t0&1) with h_{t0-1}
    {
        u32 v = 0;
        if (t0 > 0)
            v = __hip_atomic_load(&Hb[(size_t)cluster * 1024 + ((t0 - 1) & 1) * 512 + tid],
                                  __ATOMIC_RELAXED, __HIP_MEMORY_SCOPE_AGENT);
        Lhh[t0 & 1][physw] = (u16)v;
    }
    float hprev = 0.f, bhnv = 0.f;
    u16 rx = 0, rz = 0, rn = 0;
    if (fin) {
        bhnv = bhn[j];
        if (t0 > 0) hprev = hstate[bg * 512 + j];
        const u16* p = xi + (size_t)bg * Tc * 1536 + j;
        rx = p[0]; rz = p[512]; rn = p[1024];
    }
    __syncthreads();

    for (int t = t0; t < t0 + Tc; ++t) {
        const u16* lhp = Lhh[t & 1];
        float a0 = 0.f, a1 = 0.f, a2 = 0.f;
#pragma unroll
        for (int qk = 0; qk < 8; ++qk) {
            v8h h8 = *(const v8h*)&lhp[(kseg * 8 + (qk ^ kseg)) * 8];
            const v2h* hp = (const v2h*)&h8;
            v8h w0 = *(const v8h*)&Wreg[qk];
            v8h w1 = *(const v8h*)&Wreg[8 + qk];
            v8h w2 = *(const v8h*)&Wreg[16 + qk];
            const v2h* p0 = (const v2h*)&w0;
            const v2h* p1 = (const v2h*)&w1;
            const v2h* p2 = (const v2h*)&w2;
#pragma unroll
            for (int p = 0; p < 4; ++p) {
                a0 = FDOT2(p0[p], hp[p], a0);
                a1 = FDOT2(p1[p], hp[p], a1);
                a2 = FDOT2(p2[p], hp[p], a2);
            }
        }
        // reduce over kseg (lane bits 3,4,5)
#pragma unroll
        for (int d = 8; d <= 32; d <<= 1) {
            a0 += __shfl_xor(a0, d);
            a1 += __shfl_xor(a1, d);
            a2 += __shfl_xor(a2, d);
        }
        u32* slot = Hb + (size_t)cluster * 1024 + (size_t)(t & 1) * 512;
        if (fin) {
            float r = 1.f / (1.f + __expf(-(h2f(rx) + a0)));
            float z = 1.f / (1.f + __expf(-(h2f(rz) + a1)));
            float nx = h2f(rn) + r * (a2 + bhnv);
            float n = 1.f - 2.f / (__expf(2.f * nx) + 1.f);   // tanh
            float hn = (1.f - z) * n + z * hprev;
            hprev = hn;
            u16 hh = f2h(hn);
            __hip_atomic_store(&slot[j], ((u32)(u16)(t + 1) << 16) | (u32)hh,
                               __ATOMIC_RELAXED, __HIP_MEMORY_SCOPE_AGENT);
            if (layer0) hseq[((size_t)bg * 2048 + t) * 512 + j] = hh;
            if (!layer0 && t == 2047) h1last[bg * 512 + j] = hn;
            if (t + 1 < t0 + Tc) {   // prefetch xi for t+1
                const u16* p = xi + ((size_t)bg * Tc + (t + 1 - t0)) * 1536 + j;
                rx = p[0]; rz = p[512]; rn = p[1024];
            }
        }
        // poll own u32 (epoch in high 16), fill next parity buffer
        {
            const u32 target = (u32)(u16)(t + 1) << 16;
            u32* myq = &slot[tid];
            u32 qv = 0;
            for (int it = 0; it < 4000000; ++it) {
                qv = __hip_atomic_load(myq, __ATOMIC_RELAXED, __HIP_MEMORY_SCOPE_AGENT);
                if ((qv & 0xFFFF0000u) == target) break;
                __builtin_amdgcn_s_sleep(1);
            }
            Lhh[(t + 1) & 1][physw] = (u16)qv;
        }
        __syncthreads();
    }
    if (fin) hstate[bg * 512 + j] = hprev;
}

// --------------------------- final FC --------------------------------------
__global__ __launch_bounds__(64) void final_fc(const float* __restrict__ h1,
                                               const float* __restrict__ Wfc,
                                               const float* __restrict__ bfc,
                                               float* __restrict__ out) {
    int b = blockIdx.x, o = threadIdx.x;
    float acc = bfc[o];
    for (int k = 0; k < 512; ++k) acc += h1[b * 512 + k] * Wfc[k * 64 + o];
    out[b * 64 + o] = acc;
}

// --------------------------- launch ----------------------------------------

extern "C" void kernel_launch(void* const* d_in, const int* in_sizes, int n_in,
                              void* d_out, int out_size, void* d_ws, size_t ws_size,
                              hipStream_t stream) {
    const float* x    = (const float*)d_in[0];
    const float* Wi0  = (const float*)d_in[1];
    const float* bi0  = (const float*)d_in[2];
    const float* Wh0  = (const float*)d_in[3];
    const float* bhn0 = (const float*)d_in[4];
    const float* Wi1  = (const float*)d_in[5];
    const float* bi1  = (const float*)d_in[6];
    const float* Wh1  = (const float*)d_in[7];
    const float* bhn1 = (const float*)d_in[8];
    const float* Wfc  = (const float*)d_in[9];
    const float* bfc  = (const float*)d_in[10];
    float* out = (float*)d_out;
    (void)in_sizes; (void)n_in; (void)out_size;

    char* ws = (char*)d_ws;
    size_t off = 0;
    auto take = [&](size_t bytes) -> char* {
        char* p = ws + off;
        off = (off + bytes + 255) & ~(size_t)255;
        return p;
    };
    u16*  Wi0t  = (u16*)take(1536 * 256 * 2);
    u16*  Wi1t  = (u16*)take(1536 * 512 * 2);
    uint4* Wh0p = (uint4*)take(98304 * 16);
    uint4* Wh1p = (uint4*)take(98304 * 16);
    u32*  Hb0   = (u32*)take(32 * 1024 * 4);
    u32*  Hb1   = (u32*)take(32 * 1024 * 4);
    float* hstate = (float*)take(32 * 512 * 4);
    float* h1last = (float*)take(32 * 512 * 4);
    u16*  h0seq = (u16*)take((size_t)32 * 2048 * 512 * 2);
    size_t fixed_end = off;

    int Tc = 2048;
    if (ws_size > 0) {
        while (Tc > 128 &&
               fixed_end + (size_t)32 * Tc * 1536 * 2 > ws_size) Tc >>= 1;
    }
    int lgTc = 31 - __builtin_clz((u32)Tc);
    u16* xibuf = (u16*)take((size_t)32 * Tc * 1536 * 2);
    int nChunk = 2048 / Tc;

    // prep
    transpose_cast<<<dim3(48, 8), 256, 0, stream>>>(Wi0, Wi0t, 256, 1536);
    transpose_cast<<<dim3(48, 16), 256, 0, stream>>>(Wi1, Wi1t, 512, 1536);
    pack_wh<<<384, 256, 0, stream>>>(Wh0, Wh0p);
    pack_wh<<<384, 256, 0, stream>>>(Wh1, Wh1p);

    // layer 0
    for (int c = 0; c < nChunk; ++c) {
        int t0 = c * Tc;
        gemm_xi<256, true><<<dim3(24, Tc / 2), 256, 0, stream>>>(
            (const void*)x, Wi0t, bi0, xibuf, t0, lgTc);
        const u16* xi_p = xibuf; const uint4* wh_p = Wh0p; const float* bh_p = bhn0;
        u32* hb_p = Hb0; u16* hs_p = h0seq; float* h1_p = nullptr;
        float* st_p = hstate; int t0v = t0, Tcv = Tc, l0v = 1;
        void* args[] = {&xi_p, &wh_p, &bh_p, &hb_p, &hs_p, &h1_p, &st_p,
                        &t0v, &Tcv, &l0v};
        hipLaunchCooperativeKernel(gru_scan, dim3(256), dim3(512), args, 0, stream);
    }
    // layer 1
    for (int c = 0; c < nChunk; ++c) {
        int t0 = c * Tc;
        gemm_xi<512, false><<<dim3(24, Tc / 2), 256, 0, stream>>>(
            (const void*)h0seq, Wi1t, bi1, xibuf, t0, lgTc);
        const u16* xi_p = xibuf; const uint4* wh_p = Wh1p; const float* bh_p = bhn1;
        u32* hb_p = Hb1; u16* hs_p = nullptr; float* h1_p = h1last;
        float* st_p = hstate; int t0v = t0, Tcv = Tc, l0v = 0;
        void* args[] = {&xi_p, &wh_p, &bh_p, &hb_p, &hs_p, &h1_p, &st_p,
                        &t0v, &Tcv, &l0v};
        hipLaunchCooperativeKernel(gru_scan, dim3(256), dim3(512), args, 0, stream);
    }
    final_fc<<<32, 64, 0, stream>>>(h1last, Wfc, bfc, out);
}